// Round 6
// baseline (186.045 us; speedup 1.0000x reference)
//
#include <hip/hip_runtime.h>
#include <math.h>

// B,C,T = 32,1024,1024; beta=0.95; thr=1.0; sigma=10.5
#define B_     32
#define C_     1024
#define T_     1024
#define RT     92                    // tap radius (|d|>92 cannot flip any f32 spike)
#define CT     64                    // channels per block
#define TT     64                    // time chunk
#define KC     8                     // channels per thread group
#define NTY    8                     // 8 waves, 512 threads
#define NJQ    48                    // 192 source cols / 4 per b128
#define WN     (2*(RT + KC - 1) + 1) // 199 padded taps
#define WOFF   (RT + KC - 1)         // 99 center
#define NCOLS  (CT + 2*RT)           // 248 staged channel columns
#define XSTR   252                   // xsT row stride (dwords): 16B-aligned, bank-optimal
#define ISTR   68                    // Is strip row stride (dwords): 16B-aligned, conflict-free

// numpy-faithful f32 tap (identical op sequence; exp via correctly-rounded f64).
__device__ __forceinline__ float tap_value(float s, int d) {
    float u    = __fdiv_rn((float)d, s);
    float t1   = __fmul_rn(-0.5f, u);
    float t2   = __fmul_rn(t1, u);
    float e    = (float)exp((double)t2);
    float den  = __fmul_rn(s, sqrtf(6.2831854820251465f));
    float coef = __fdiv_rn(1.0f, den);
    return __fmul_rn(coef, e);
}

__global__ void init_w_kernel(const float* __restrict__ sigma, float* __restrict__ gw) {
    int i = threadIdx.x;
    if (i < WN) {
        int d = i - WOFF;
        gw[i] = (d >= -RT && d <= RT) ? tap_value(sigma[0], d) : 0.0f;
    }
}

// Layout: xsT[t][chan_col] (transposed) -> conv reads are ds_read_b128 along j.
// Thread (tx,ty): computes channels c0+ty*8+k (k=0..7) at t = t0+tx.
// Wave ty owns its 8 channels across all 64 t -> wave-local I strip + scan.
template <bool GW>
__global__ __launch_bounds__(512, 4) void snn_v6(
    const float* __restrict__ x, const float* __restrict__ sigma,
    const float* __restrict__ gw, float* __restrict__ out)
{
    __shared__ __align__(16) float xsT[TT * XSTR];        // 64512 B
    __shared__ __align__(16) float IsS[NTY * KC * ISTR];  // 17408 B (total 81920)

    const int tx   = threadIdx.x;       // t lane 0..63
    const int ty   = threadIdx.y;       // wave 0..7
    const int flat = ty * 64 + tx;
    const int b    = blockIdx.y;
    const int c0   = blockIdx.x * CT;
    const int rb   = ty * KC;           // first local channel of this wave

    const float* xb = x   + (size_t)b * ((size_t)C_ * T_);
    float*       ob = out + (size_t)b * ((size_t)C_ * T_);

    float sv = 0.0f;
    if (!GW) sv = sigma[0];             // fallback only

    // ---- register staging (T14): (r = chan col, c4 = t-quad) ----
    // lanes of a wave span 16 r x 4 c4 -> conflict-free transposed LDS writes.
    float4 stg[2][4];                   // statically indexed only
    const int rB  = (flat >> 2);        // 0..127
    const int c4B = (flat & 3);         // 0..3

#define STAGE_LOAD(T0)                                                          \
    _Pragma("unroll")                                                           \
    for (int i1 = 0; i1 < 2; ++i1) {                                            \
        _Pragma("unroll")                                                       \
        for (int i2 = 0; i2 < 4; ++i2) {                                        \
            int r  = rB + 128 * i1;                                             \
            int c4 = c4B + 4 * i2;                                              \
            int c  = c0 - RT + r;                                               \
            float4 v = make_float4(0.f, 0.f, 0.f, 0.f);                         \
            if (r < NCOLS && c >= 0 && c < C_)                                  \
                v = *(const float4*)(xb + (size_t)c * T_ + (T0) + c4 * 4);      \
            stg[i1][i2] = v;                                                    \
        }                                                                       \
    }

#define STAGE_WRITE()                                                           \
    _Pragma("unroll")                                                           \
    for (int i1 = 0; i1 < 2; ++i1) {                                            \
        _Pragma("unroll")                                                       \
        for (int i2 = 0; i2 < 4; ++i2) {                                        \
            int r  = rB + 128 * i1;                                             \
            int c4 = c4B + 4 * i2;                                              \
            if (r < NCOLS) {                                                    \
                xsT[(4 * c4 + 0) * XSTR + r] = stg[i1][i2].x;                   \
                xsT[(4 * c4 + 1) * XSTR + r] = stg[i1][i2].y;                   \
                xsT[(4 * c4 + 2) * XSTR + r] = stg[i1][i2].z;                   \
                xsT[(4 * c4 + 3) * XSTR + r] = stg[i1][i2].w;                   \
            }                                                                   \
        }                                                                       \
    }

    STAGE_LOAD(0);

    float mem = 0.0f;                       // channel c0+rb+tx, lanes tx<8 only
    float* strip = IsS + ty * (KC * ISTR);  // wave-local I strip

    for (int kk = 0; kk < T_ / TT; ++kk) {
        const int t0 = kk * TT;

        STAGE_WRITE();          // chunk kk -> xsT (vmcnt auto)
        __syncthreads();        // xsT ready for all waves

        if (kk < T_ / TT - 1) { STAGE_LOAD(t0 + TT); }  // hides under conv

        // ---- conv: 48 x ds_read_b128 along j; ascending-j f32 FMA chains ----
        float acc[KC];
#pragma unroll
        for (int k = 0; k < KC; ++k) acc[k] = 0.0f;

        const float* xrow = &xsT[tx * XSTR + rb];
#pragma unroll 4
        for (int jq = 0; jq < NJQ; ++jq) {
            float4 xv = *(const float4*)(xrow + 4 * jq);
#pragma unroll
            for (int qq = 0; qq < 4; ++qq) {
                float xs1 = (qq == 0) ? xv.x : (qq == 1) ? xv.y : (qq == 2) ? xv.z : xv.w;
#pragma unroll
                for (int k = 0; k < KC; ++k) {
                    // global j - c = 4jq+qq-k-RT; tap idx = 4jq+qq+7-k (wave-uniform -> SGPR)
                    float wv;
                    if (GW) {
                        wv = gw[4 * jq + qq + 7 - k];
                    } else {
                        int d = 4 * jq + qq + 7 - k - WOFF;
                        wv = (d >= -RT && d <= RT) ? tap_value(sv, d) : 0.0f;
                    }
                    acc[k] = fmaf(wv, xs1, acc[k]);
                }
            }
        }

        // I = x - conv; write into wave-local strip (no barrier needed)
        float4 xoA = *(const float4*)(xrow + RT);
        float4 xoB = *(const float4*)(xrow + RT + 4);
        {
            float xo[KC] = {xoA.x, xoA.y, xoA.z, xoA.w, xoB.x, xoB.y, xoB.z, xoB.w};
#pragma unroll
            for (int k = 0; k < KC; ++k)
                strip[k * ISTR + tx] = __fsub_rn(xo[k], acc[k]);
        }

        // ---- wave-local LIF scan (lanes tx<8; k = tx). Spikes -> global.  ----
        // reset = RN(soft + RN(1-soft)) == 1.0f exactly for soft in (0,0.5),
        // so the reference's atan surrogate is bit-exactly a compare.
        if (tx < KC) {
            float m = mem;
            const float* srow = strip + tx * ISTR;
            float* orow = ob + (size_t)(c0 + rb + tx) * T_ + t0;
#pragma unroll 4
            for (int q = 0; q < TT / 4; ++q) {
                float4 Iq = *(const float4*)(srow + 4 * q);
                float4 s;
#pragma unroll
                for (int qq = 0; qq < 4; ++qq) {
                    float Ivv = (qq == 0) ? Iq.x : (qq == 1) ? Iq.y : (qq == 2) ? Iq.z : Iq.w;
                    float r   = (m > 1.0f) ? 1.0f : 0.0f;
                    m = __fsub_rn(__fadd_rn(__fmul_rn(0.95f, m), Ivv), r);
                    float sp  = (m > 1.0f) ? 1.0f : 0.0f;
                    if (qq == 0) s.x = sp; else if (qq == 1) s.y = sp;
                    else if (qq == 2) s.z = sp; else s.w = sp;
                }
                *(float4*)(orow + 4 * q) = s;
            }
            mem = m;
        }
        __syncthreads();        // all conv xsT reads done before next STAGE_WRITE
    }
#undef STAGE_LOAD
#undef STAGE_WRITE
}

extern "C" void kernel_launch(void* const* d_in, const int* in_sizes, int n_in,
                              void* d_out, int out_size, void* d_ws, size_t ws_size,
                              hipStream_t stream) {
    const float* x     = (const float*)d_in[0];   // [32,1024,1024] f32
    const float* sigma = (const float*)d_in[1];   // [1] f32
    float* out = (float*)d_out;

    dim3 grid(C_ / CT, B_);   // (16, 32) = 512 blocks
    dim3 block(64, NTY);      // 512 threads, 8 waves

    if (ws_size >= WN * sizeof(float)) {
        float* gw = (float*)d_ws;
        init_w_kernel<<<1, 256, 0, stream>>>(sigma, gw);
        snn_v6<true><<<grid, block, 0, stream>>>(x, sigma, gw, out);
    } else {
        snn_v6<false><<<grid, block, 0, stream>>>(x, sigma, nullptr, out);
    }
}